// Round 8
// baseline (188.438 us; speedup 1.0000x reference)
//
#include <hip/hip_runtime.h>
#include <hip/hip_bf16.h>
#include <stdint.h>

// ---------- types & helpers ----------
typedef __attribute__((ext_vector_type(8))) short bf16x8;
typedef __attribute__((ext_vector_type(4))) short short4v;
typedef __attribute__((ext_vector_type(4))) float f32x4;

#define MFMA16x16x32 __builtin_amdgcn_mfma_f32_16x16x32_bf16

__device__ __forceinline__ short f2b(float f) {
  union { float f; uint32_t u; } x;
  x.f = f;
  uint32_t u = x.u;
  uint32_t r = (u + 0x7FFFu + ((u >> 16) & 1u)) >> 16;  // RNE
  return (short)(uint16_t)r;
}

// HW packed fp32->bf16 (RNE), no builtin on gfx950 (m240) -> inline asm
__device__ __forceinline__ uint32_t cvt_pk_bf16(float lo, float hi) {
  uint32_t r;
  asm volatile("v_cvt_pk_bf16_f32 %0, %1, %2" : "=v"(r) : "v"(lo), "v"(hi));
  return r;
}
// raw v_exp_f32 = 2^x
__device__ __forceinline__ float exp2_fast(float x) {
  float r;
  asm volatile("v_exp_f32 %0, %1" : "=v"(r) : "v"(x));
  return r;
}
__device__ __forceinline__ bf16x8 cvt8(const float4 a, const float4 b) {
  union { uint32_t u[4]; bf16x8 v; } o;
  o.u[0] = cvt_pk_bf16(a.x, a.y);
  o.u[1] = cvt_pk_bf16(a.z, a.w);
  o.u[2] = cvt_pk_bf16(b.x, b.y);
  o.u[3] = cvt_pk_bf16(b.z, b.w);
  return o.v;
}

// async global->LDS, 16B per lane; LDS dest = wave-uniform base + lane*16
__device__ __forceinline__ void async_copy16(const void* g, void* l) {
  __builtin_amdgcn_global_load_lds(
      (const __attribute__((address_space(1))) void*)g,
      (__attribute__((address_space(3))) void*)l, 16, 0, 0);
}

// ---------- weight transpose+convert: Wt[n][k] = bf16(W[k][n]), 4x 1024x1024 ----------
__global__ void transpose4_kernel(const float* __restrict__ W0,
                                  const float* __restrict__ W1,
                                  const float* __restrict__ W2,
                                  const float* __restrict__ W3,
                                  short* __restrict__ Wt) {
  __shared__ short tile[64][72];
  const int mat = blockIdx.z;
  const float* W = (mat == 0) ? W0 : (mat == 1) ? W1 : (mat == 2) ? W2 : W3;
  short* Wo = Wt + (size_t)mat * 1024 * 1024;
  const int r0 = blockIdx.y * 64;  // src row base (k)
  const int c0 = blockIdx.x * 64;  // src col base (n)
  const int t = threadIdx.x;
#pragma unroll
  for (int i = 0; i < 4; ++i) {
    const int lin = i * 1024 + t * 4;
    const int r = lin >> 6, c = lin & 63;
    const float4 v = *(const float4*)&W[(size_t)(r0 + r) * 1024 + c0 + c];
    tile[r][c + 0] = f2b(v.x);
    tile[r][c + 1] = f2b(v.y);
    tile[r][c + 2] = f2b(v.z);
    tile[r][c + 3] = f2b(v.w);
  }
  __syncthreads();
#pragma unroll
  for (int i = 0; i < 2; ++i) {
    const int lin = i * 2048 + t * 8;
    const int r = lin >> 6, c = lin & 63;  // r = out row (n), c = out col (k)
    bf16x8 ov;
#pragma unroll
    for (int jj = 0; jj < 8; ++jj) ov[jj] = tile[c + jj][r];
    *(bf16x8*)&Wo[(size_t)(c0 + r) * 1024 + r0 + c] = ov;
  }
}

// ---------- QKV projection GEMM + bias ----------
// A fp32 [M][K] read DIRECT-to-register as MFMA fragments (fp32->bf16 cvt in
// regs; duplicate reads served by same-XCD L2 via the T1 tile swizzle).
// B (weights) double-buffered in LDS; stage for kt+1 issued AFTER the barrier
// -> it has the whole MFMA+A-load window to land (drained by next barrier's
// implicit vmcnt(0)). ONE barrier per K-step. 32 KB LDS -> 3 blocks/CU.
__launch_bounds__(256, 2)
__global__ void gemm_qkv_kernel(const float* __restrict__ A0,
                                const float* __restrict__ A1,
                                const float* __restrict__ A2,
                                const short* __restrict__ WtBase,
                                const float* __restrict__ b0,
                                const float* __restrict__ b1,
                                const float* __restrict__ b2,
                                short* __restrict__ C0,
                                short* __restrict__ C1,
                                short* __restrict__ Vt) {
  const int K = 1024;
  __shared__ short Bs[2][128 * 64];

  const int y = blockIdx.y;
  const float* A = (y == 0) ? A0 : (y == 1) ? A1 : A2;
  const short* Wt = WtBase + (size_t)y * 1024 * 1024;
  const float* bias = (y == 0) ? b0 : (y == 1) ? b1 : b2;

  const int tm = blockIdx.x & 31;  // fast index -> same-XCD siblings share tm
  const int tn = blockIdx.x >> 5;
  const int m0 = tm * 128, n0 = tn * 128;

  const int tid = threadIdx.x;
  const int lane = tid & 63;
  const int w = tid >> 6;
  const int wr = w >> 1, wc = w & 1;
  const int hi = lane >> 4, cc = lane & 15;

  const int srow = lane >> 3;
  const int schunk = lane & 7;

  f32x4 acc[4][4] = {};

  // prologue: stage B(0) into Bs[0]
#pragma unroll
  for (int i = 0; i < 4; ++i) {
    const int ri = w * 4 + i;
    const int row = ri * 8 + srow;
    const int gch = schunk ^ (row & 7);
    async_copy16(Wt + (size_t)(n0 + row) * K + gch * 8, &Bs[0][ri * 512]);
  }

  for (int kt = 0; kt < 16; ++kt) {
    const int cur = kt & 1;
    const int k0 = kt * 64;

    // A fragments: direct global fp32 -> bf16 in regs
    bf16x8 af[2][4];
#pragma unroll
    for (int kk = 0; kk < 2; ++kk)
#pragma unroll
      for (int x = 0; x < 4; ++x) {
        const float* src = A + (size_t)(m0 + wr * 64 + x * 16 + cc) * 1024 +
                           k0 + kk * 32 + hi * 8;
        af[kk][x] = cvt8(*(const float4*)src, *(const float4*)(src + 4));
      }

    __syncthreads();  // drains vmcnt -> B(kt) arrived; Bs[cur^1] readers done

    if (kt < 15) {  // post-barrier issue: overlaps the MFMA phase below
      const int k1 = k0 + 64;
#pragma unroll
      for (int i = 0; i < 4; ++i) {
        const int ri = w * 4 + i;
        const int row = ri * 8 + srow;
        const int gch = schunk ^ (row & 7);
        async_copy16(Wt + (size_t)(n0 + row) * K + (k1 + gch * 8),
                     &Bs[cur ^ 1][ri * 512]);
      }
    }

#pragma unroll
    for (int kk = 0; kk < 2; ++kk) {
      bf16x8 bfr[4];
#pragma unroll
      for (int yy = 0; yy < 4; ++yy) {
        const int gch = kk * 4 + hi;
        const int rowB = wc * 64 + yy * 16 + cc;
        bfr[yy] = *(const bf16x8*)&Bs[cur][rowB * 64 + ((gch ^ (rowB & 7)) << 3)];
      }
#pragma unroll
      for (int x = 0; x < 4; ++x)
#pragma unroll
        for (int yy = 0; yy < 4; ++yy)
          acc[x][yy] = MFMA16x16x32(af[kk][x], bfr[yy], acc[x][yy], 0, 0, 0);
    }
  }

  // epilogue (C/D layout: col=lane&15, row=(lane>>4)*4+r)
  short* Cout = (y == 0) ? C0 : C1;
#pragma unroll
  for (int x = 0; x < 4; ++x) {
    const int rbase = m0 + wr * 64 + x * 16 + (hi << 2);
#pragma unroll
    for (int yy = 0; yy < 4; ++yy) {
      const int col = n0 + wc * 64 + yy * 16 + cc;
      const float bv = bias[col];
      if (y == 2) {
        const int b = rbase >> 11, s = rbase & 2047;
        const int hh = col >> 6, d = col & 63;
        short4v pack;
#pragma unroll
        for (int r = 0; r < 4; ++r) pack[r] = f2b(acc[x][yy][r] + bv);
        *(short4v*)&Vt[((size_t)(b * 16 + hh) * 64 + d) * 2048 + s] = pack;
      } else {
#pragma unroll
        for (int r = 0; r < 4; ++r)
          Cout[(size_t)(rbase + r) * 1024 + col] = f2b(acc[x][yy][r] + bv);
      }
    }
  }
}

// ---------- output projection GEMM (bf16 A direct-to-reg, fp32 out) ----------
__launch_bounds__(256, 2)
__global__ void gemm_out_kernel(const short* __restrict__ A,
                                const short* __restrict__ Wt,
                                const float* __restrict__ bias,
                                float* __restrict__ C) {
  const int N = 1024, K = 1024;
  __shared__ short Bs[2][128 * 64];

  const int tm = blockIdx.x & 31;
  const int tn = blockIdx.x >> 5;
  const int m0 = tm * 128, n0 = tn * 128;

  const int tid = threadIdx.x;
  const int lane = tid & 63;
  const int w = tid >> 6;
  const int wr = w >> 1, wc = w & 1;
  const int hi = lane >> 4, cc = lane & 15;
  const int srow = lane >> 3, schunk = lane & 7;

  f32x4 acc[4][4] = {};

  // prologue: stage B(0)
#pragma unroll
  for (int i = 0; i < 4; ++i) {
    const int ri = w * 4 + i;
    const int row = ri * 8 + srow;
    const int gch = schunk ^ (row & 7);
    async_copy16(Wt + (size_t)(n0 + row) * K + gch * 8, &Bs[0][ri * 512]);
  }

  for (int kt = 0; kt < 16; ++kt) {
    const int cur = kt & 1;
    const int k0 = kt * 64;

    // A fragments: direct global bf16 (one 16B load per fragment)
    bf16x8 af[2][4];
#pragma unroll
    for (int kk = 0; kk < 2; ++kk)
#pragma unroll
      for (int x = 0; x < 4; ++x)
        af[kk][x] = *(const bf16x8*)&A[(size_t)(m0 + wr * 64 + x * 16 + cc) * 1024 +
                                       k0 + kk * 32 + hi * 8];

    __syncthreads();

    if (kt < 15) {
      const int k1 = k0 + 64;
#pragma unroll
      for (int i = 0; i < 4; ++i) {
        const int ri = w * 4 + i;
        const int row = ri * 8 + srow;
        const int gch = schunk ^ (row & 7);
        async_copy16(Wt + (size_t)(n0 + row) * K + (k1 + gch * 8),
                     &Bs[cur ^ 1][ri * 512]);
      }
    }

#pragma unroll
    for (int kk = 0; kk < 2; ++kk) {
      bf16x8 bfr[4];
#pragma unroll
      for (int yy = 0; yy < 4; ++yy) {
        const int gch = kk * 4 + hi;
        const int rowB = wc * 64 + yy * 16 + cc;
        bfr[yy] = *(const bf16x8*)&Bs[cur][rowB * 64 + ((gch ^ (rowB & 7)) << 3)];
      }
#pragma unroll
      for (int x = 0; x < 4; ++x)
#pragma unroll
        for (int yy = 0; yy < 4; ++yy)
          acc[x][yy] = MFMA16x16x32(af[kk][x], bfr[yy], acc[x][yy], 0, 0, 0);
    }
  }

#pragma unroll
  for (int x = 0; x < 4; ++x) {
    const int rbase = m0 + wr * 64 + x * 16 + (hi << 2);
#pragma unroll
    for (int yy = 0; yy < 4; ++yy) {
      const int col = n0 + wc * 64 + yy * 16 + cc;
      const float bv = bias[col];
#pragma unroll
      for (int r = 0; r < 4; ++r)
        C[(size_t)(rbase + r) * N + col] = acc[x][yy][r] + bv;
    }
  }
}

// ---------- flash attention (swapped ops, 32 q/wave, static-shift softmax) ----------
// grid (16, 16, 2) = 512 blocks; 4 waves x 32 q-rows; KVBLK=64, K/V dbuf.
__launch_bounds__(256, 2)
__global__ void attn_kernel(const short* __restrict__ qh,
                            const short* __restrict__ kh,
                            const short* __restrict__ Vt,
                            short* __restrict__ concat) {
  const int S = 2048;
  const float CL2 = 0.18033688011112042f;  // 0.125 * log2(e)
  __shared__ short Ks[2][64 * 64];
  __shared__ short Vs[2][64 * 64];
  __shared__ short Ps[4 * 32 * 64];

  const int qb = blockIdx.x;
  const int h = blockIdx.y;
  const int b = blockIdx.z;
  const int tid = threadIdx.x, lane = tid & 63, w = tid >> 6;
  const int hi = lane >> 4, cc = lane & 15;

  const size_t rowbase = (size_t)b * S;
  const int q0 = qb * 128 + w * 32;

  // Q fragments, B-operand: col = q, k = hi*8+i (+32 per kk); 2 q-frags
  bf16x8 qf[2][2];
#pragma unroll
  for (int aq = 0; aq < 2; ++aq)
#pragma unroll
    for (int kk = 0; kk < 2; ++kk) {
      const int col = h * 64 + kk * 32 + hi * 8;
      qf[aq][kk] =
          *(const bf16x8*)&qh[(rowbase + q0 + aq * 16 + cc) * 1024 + col];
    }

  f32x4 oacc[2][4] = {};
  float l[2] = {0.f, 0.f};

  const short* Vth = Vt + (size_t)(b * 16 + h) * 64 * 2048;
  short* Pw = &Ps[w * 2048];
  const int srow = lane >> 3, schunk = lane & 7;
  const int e0 = (cc >> 3) & 1;

  // prologue: stage tile 0 into buf 0
#pragma unroll
  for (int i = 0; i < 2; ++i) {
    const int ri = w * 2 + i;
    const int row = ri * 8 + srow;
    const int gch = schunk ^ (row & 7);
    async_copy16(&kh[(rowbase + row) * 1024 + h * 64 + gch * 8], &Ks[0][ri * 512]);
    async_copy16(&Vth[(size_t)row * 2048 + gch * 8], &Vs[0][ri * 512]);
  }
  __syncthreads();

  for (int t = 0; t < S / 64; ++t) {
    const int cur = t & 1;
    if (t + 1 < S / 64) {  // issue next-tile stage before computing current
      const int kv0 = (t + 1) * 64;
#pragma unroll
      for (int i = 0; i < 2; ++i) {
        const int ri = w * 2 + i;
        const int row = ri * 8 + srow;
        const int gch = schunk ^ (row & 7);
        async_copy16(&kh[(rowbase + kv0 + row) * 1024 + h * 64 + gch * 8],
                     &Ks[cur ^ 1][ri * 512]);
        async_copy16(&Vth[(size_t)row * 2048 + kv0 + gch * 8],
                     &Vs[cur ^ 1][ri * 512]);
      }
    }

    // QK^T swapped: sacc[aq][n] = mfma(K_frag(n), Q_aq) -> D[kv][q]
    f32x4 sacc[2][4] = {};
#pragma unroll
    for (int kk = 0; kk < 2; ++kk) {
      bf16x8 kf[4];
#pragma unroll
      for (int n = 0; n < 4; ++n) {
        const int row = n * 16 + cc;
        const int ch = (kk * 4 + hi) ^ (cc & 7);
        kf[n] = *(const bf16x8*)&Ks[cur][row * 64 + (ch << 3)];
      }
#pragma unroll
      for (int aq = 0; aq < 2; ++aq)
#pragma unroll
        for (int n = 0; n < 4; ++n)
          sacc[aq][n] = MFMA16x16x32(kf[n], qf[aq][kk], sacc[aq][n], 0, 0, 0);
    }

    // static-shift softmax: p = 2^(s*CL2); lane owns q-row aq*16+cc
#pragma unroll
    for (int aq = 0; aq < 2; ++aq) {
      const int qrow = aq * 16 + cc;
#pragma unroll
      for (int n = 0; n < 4; ++n) {
        const float p0 = exp2_fast(sacc[aq][n][0] * CL2);
        const float p1 = exp2_fast(sacc[aq][n][1] * CL2);
        const float p2 = exp2_fast(sacc[aq][n][2] * CL2);
        const float p3 = exp2_fast(sacc[aq][n][3] * CL2);
        l[aq] += (p0 + p1) + (p2 + p3);
        const uint32_t u0 = cvt_pk_bf16(p0, p1);
        const uint32_t u1 = cvt_pk_bf16(p2, p3);
        const int chunk = (2 * n + (hi >> 1)) ^ (cc & 7);
        const int base = qrow * 64 + (chunk << 3) + ((hi & 1) << 2);
        // two b32 writes, word-parity split -> 32 distinct banks per phase
        *(uint32_t*)&Pw[base + (e0 << 1)] = e0 ? u1 : u0;
        *(uint32_t*)&Pw[base + ((e0 ^ 1) << 1)] = e0 ? u0 : u1;
      }
    }

    // PV swapped: oacc[aq][n] = mfma(V^T_frag(n), P_aq) -> D[d][q]
#pragma unroll
    for (int kvh = 0; kvh < 2; ++kvh) {
      const int ch = (kvh * 4 + hi) ^ (cc & 7);
      bf16x8 pf[2], vf[4];
#pragma unroll
      for (int aq = 0; aq < 2; ++aq)
        pf[aq] = *(const bf16x8*)&Pw[(aq * 16 + cc) * 64 + (ch << 3)];
#pragma unroll
      for (int n = 0; n < 4; ++n) {
        const int row = n * 16 + cc;
        vf[n] = *(const bf16x8*)&Vs[cur][row * 64 + (ch << 3)];
      }
#pragma unroll
      for (int aq = 0; aq < 2; ++aq)
#pragma unroll
        for (int n = 0; n < 4; ++n)
          oacc[aq][n] = MFMA16x16x32(vf[n], pf[aq], oacc[aq][n], 0, 0, 0);
    }
    __syncthreads();  // next-tile stage drained; buf[cur] free to overwrite
  }

  // epilogue: finish row-sums across the 4 lanes sharing q, normalize, store
#pragma unroll
  for (int aq = 0; aq < 2; ++aq) {
    float lv = l[aq];
    lv += __shfl_xor(lv, 16);
    lv += __shfl_xor(lv, 32);
    const float inv = 1.0f / lv;
    const size_t grow = rowbase + q0 + aq * 16 + cc;
#pragma unroll
    for (int n = 0; n < 4; ++n)
#pragma unroll
      for (int r = 0; r < 4; ++r) {
        const int d = n * 16 + hi * 4 + r;
        concat[grow * 1024 + h * 64 + d] = f2b(oacc[aq][n][r] * inv);
      }
  }
}

// ---------- launch ----------
extern "C" void kernel_launch(void* const* d_in, const int* in_sizes, int n_in,
                              void* d_out, int out_size, void* d_ws, size_t ws_size,
                              hipStream_t stream) {
  const float* q = (const float*)d_in[0];
  const float* k = (const float*)d_in[1];
  const float* v = (const float*)d_in[2];
  const float* WQ = (const float*)d_in[3];
  const float* bQ = (const float*)d_in[4];
  const float* WK = (const float*)d_in[5];
  const float* bK = (const float*)d_in[6];
  const float* WV = (const float*)d_in[7];
  const float* bV = (const float*)d_in[8];
  const float* WO = (const float*)d_in[9];
  const float* bO = (const float*)d_in[10];

  char* ws = (char*)d_ws;
  const size_t MB = 1024 * 1024;
  short* Wt = (short*)ws;                  // 8 MB (WQ,WK,WV,WO transposed bf16)
  short* qh = (short*)(ws + 8 * MB);       // 8 MB
  short* kh = (short*)(ws + 16 * MB);      // 8 MB
  short* Vt = (short*)(ws + 24 * MB);      // 8 MB
  short* concat = (short*)(ws + 32 * MB);  // 8 MB -> 40 MB total

  // 1) weights: transpose + convert
  transpose4_kernel<<<dim3(16, 16, 4), 256, 0, stream>>>(WQ, WK, WV, WO, Wt);
  // 2) QKV projections (fp32 A direct-to-reg); V-transpose fused
  gemm_qkv_kernel<<<dim3(256, 3), 256, 0, stream>>>(
      q, k, v, Wt, bQ, bK, bV, qh, kh, Vt);
  // 3) flash attention -> concat [b*s][h*hd]
  attn_kernel<<<dim3(16, 16, 2), 256, 0, stream>>>(qh, kh, Vt, concat);
  // 4) output projection -> d_out (fp32)
  gemm_out_kernel<<<256, 256, 0, stream>>>(concat, Wt + 3 * MB, bO,
                                           (float*)d_out);
}

// Round 9
// 137.164 us; speedup vs baseline: 1.3738x; 1.3738x over previous
//
#include <hip/hip_runtime.h>
#include <hip/hip_bf16.h>
#include <stdint.h>

// ---------- types & helpers ----------
typedef __attribute__((ext_vector_type(8))) short bf16x8;
typedef __attribute__((ext_vector_type(4))) short short4v;
typedef __attribute__((ext_vector_type(4))) float f32x4;

#define MFMA16x16x32 __builtin_amdgcn_mfma_f32_16x16x32_bf16

__device__ __forceinline__ short f2b(float f) {
  union { float f; uint32_t u; } x;
  x.f = f;
  uint32_t u = x.u;
  uint32_t r = (u + 0x7FFFu + ((u >> 16) & 1u)) >> 16;  // RNE
  return (short)(uint16_t)r;
}

// HW packed fp32->bf16 (RNE), no builtin on gfx950 (m240) -> inline asm
__device__ __forceinline__ uint32_t cvt_pk_bf16(float lo, float hi) {
  uint32_t r;
  asm volatile("v_cvt_pk_bf16_f32 %0, %1, %2" : "=v"(r) : "v"(lo), "v"(hi));
  return r;
}
// raw v_exp_f32 = 2^x
__device__ __forceinline__ float exp2_fast(float x) {
  float r;
  asm volatile("v_exp_f32 %0, %1" : "=v"(r) : "v"(x));
  return r;
}
__device__ __forceinline__ bf16x8 cvt8(const float4 a, const float4 b) {
  union { uint32_t u[4]; bf16x8 v; } o;
  o.u[0] = cvt_pk_bf16(a.x, a.y);
  o.u[1] = cvt_pk_bf16(a.z, a.w);
  o.u[2] = cvt_pk_bf16(b.x, b.y);
  o.u[3] = cvt_pk_bf16(b.z, b.w);
  return o.v;
}

// async global->LDS, 16B per lane; LDS dest = wave-uniform base + lane*16
__device__ __forceinline__ void async_copy16(const void* g, void* l) {
  __builtin_amdgcn_global_load_lds(
      (const __attribute__((address_space(1))) void*)g,
      (__attribute__((address_space(3))) void*)l, 16, 0, 0);
}

// ---------- fp32 -> bf16 convert, 3 tensors, 8 elems/thread ----------
__global__ void cvt3_kernel(const float* __restrict__ x0,
                            const float* __restrict__ x1,
                            const float* __restrict__ x2,
                            short* __restrict__ y0,
                            short* __restrict__ y1,
                            short* __restrict__ y2) {
  const int t = blockIdx.y;
  const float* x = (t == 0) ? x0 : (t == 1) ? x1 : x2;
  short* yp = (t == 0) ? y0 : (t == 1) ? y1 : y2;
  const int i = blockIdx.x * blockDim.x + threadIdx.x;  // 0..524287
  const float4 a = ((const float4*)x)[2 * i];
  const float4 b = ((const float4*)x)[2 * i + 1];
  ((bf16x8*)yp)[i] = cvt8(a, b);
}

// ---------- weight transpose+convert: Wt[n][k] = bf16(W[k][n]), 4x 1024x1024 ----------
__global__ void transpose4_kernel(const float* __restrict__ W0,
                                  const float* __restrict__ W1,
                                  const float* __restrict__ W2,
                                  const float* __restrict__ W3,
                                  short* __restrict__ Wt) {
  __shared__ short tile[64][72];
  const int mat = blockIdx.z;
  const float* W = (mat == 0) ? W0 : (mat == 1) ? W1 : (mat == 2) ? W2 : W3;
  short* Wo = Wt + (size_t)mat * 1024 * 1024;
  const int r0 = blockIdx.y * 64;  // src row base (k)
  const int c0 = blockIdx.x * 64;  // src col base (n)
  const int t = threadIdx.x;
#pragma unroll
  for (int i = 0; i < 4; ++i) {
    const int lin = i * 1024 + t * 4;
    const int r = lin >> 6, c = lin & 63;
    const float4 v = *(const float4*)&W[(size_t)(r0 + r) * 1024 + c0 + c];
    tile[r][c + 0] = f2b(v.x);
    tile[r][c + 1] = f2b(v.y);
    tile[r][c + 2] = f2b(v.z);
    tile[r][c + 3] = f2b(v.w);
  }
  __syncthreads();
#pragma unroll
  for (int i = 0; i < 2; ++i) {
    const int lin = i * 2048 + t * 8;
    const int r = lin >> 6, c = lin & 63;  // r = out row (n), c = out col (k)
    bf16x8 ov;
#pragma unroll
    for (int jj = 0; jj < 8; ++jj) ov[jj] = tile[c + jj][r];
    *(bf16x8*)&Wo[(size_t)(c0 + r) * 1024 + r0 + c] = ov;
  }
}

// ---------- QKV projection GEMM + bias (bf16 A via global_load_lds) ----------
// slice = blockIdx.y + ybase selects tensor; slice 2 writes Vt transposed.
// Proven round-7 structure: As/Bs single-buffer, 2 barriers/K-step,
// XCD-aware tile map (tm = x&31 fast -> same-XCD siblings share A rows).
__launch_bounds__(256, 2)
__global__ void gemm_qkv_kernel(const short* __restrict__ A0,
                                const short* __restrict__ A1,
                                const short* __restrict__ A2,
                                const short* __restrict__ WtBase,
                                const float* __restrict__ b0,
                                const float* __restrict__ b1,
                                const float* __restrict__ b2,
                                short* __restrict__ C0,
                                short* __restrict__ C1,
                                short* __restrict__ Vt,
                                int ybase) {
  const int K = 1024;
  __shared__ short As[128 * 64];
  __shared__ short Bs[128 * 64];

  const int y = blockIdx.y + ybase;
  const short* A = (y == 0) ? A0 : (y == 1) ? A1 : A2;
  const short* Wt = WtBase + (size_t)y * 1024 * 1024;
  const float* bias = (y == 0) ? b0 : (y == 1) ? b1 : b2;

  const int tm = blockIdx.x & 31;  // fast index -> same-XCD siblings share tm
  const int tn = blockIdx.x >> 5;
  const int m0 = tm * 128, n0 = tn * 128;

  const int tid = threadIdx.x;
  const int lane = tid & 63;
  const int w = tid >> 6;
  const int wr = w >> 1, wc = w & 1;
  const int hi = lane >> 4, cc = lane & 15;
  const int srow = lane >> 3, schunk = lane & 7;

  f32x4 acc[4][4] = {};

  for (int kt = 0; kt < 16; ++kt) {
    const int k0 = kt * 64;
#pragma unroll
    for (int i = 0; i < 4; ++i) {
      const int ri = w * 4 + i;
      const int row = ri * 8 + srow;
      const int gch = schunk ^ (row & 7);
      async_copy16(A + (size_t)(m0 + row) * K + (k0 + gch * 8), &As[ri * 512]);
      async_copy16(Wt + (size_t)(n0 + row) * K + (k0 + gch * 8), &Bs[ri * 512]);
    }
    __syncthreads();
#pragma unroll
    for (int kk = 0; kk < 2; ++kk) {
      bf16x8 af[4], bfr[4];
#pragma unroll
      for (int x = 0; x < 4; ++x) {
        const int gch = kk * 4 + hi;
        const int rowA = wr * 64 + x * 16 + cc;
        af[x] = *(const bf16x8*)&As[rowA * 64 + ((gch ^ (rowA & 7)) << 3)];
        const int rowB = wc * 64 + x * 16 + cc;
        bfr[x] = *(const bf16x8*)&Bs[rowB * 64 + ((gch ^ (rowB & 7)) << 3)];
      }
#pragma unroll
      for (int x = 0; x < 4; ++x)
#pragma unroll
        for (int yy = 0; yy < 4; ++yy)
          acc[x][yy] = MFMA16x16x32(af[x], bfr[yy], acc[x][yy], 0, 0, 0);
    }
    __syncthreads();
  }

  // epilogue (C/D layout: col=lane&15, row=(lane>>4)*4+r)
  short* Cout = (y == 0) ? C0 : C1;
#pragma unroll
  for (int x = 0; x < 4; ++x) {
    const int rbase = m0 + wr * 64 + x * 16 + (hi << 2);
#pragma unroll
    for (int yy = 0; yy < 4; ++yy) {
      const int col = n0 + wc * 64 + yy * 16 + cc;
      const float bv = bias[col];
      if (y == 2) {
        const int b = rbase >> 11, s = rbase & 2047;
        const int hh = col >> 6, d = col & 63;
        short4v pack;
#pragma unroll
        for (int r = 0; r < 4; ++r) pack[r] = f2b(acc[x][yy][r] + bv);
        *(short4v*)&Vt[((size_t)(b * 16 + hh) * 64 + d) * 2048 + s] = pack;
      } else {
#pragma unroll
        for (int r = 0; r < 4; ++r)
          Cout[(size_t)(rbase + r) * 1024 + col] = f2b(acc[x][yy][r] + bv);
      }
    }
  }
}

// ---------- output projection GEMM (bf16 A, fp32 out), XCD-aware tile map ----------
__launch_bounds__(256, 2)
__global__ void gemm_out_kernel(const short* __restrict__ A,
                                const short* __restrict__ Wt,
                                const float* __restrict__ bias,
                                float* __restrict__ C) {
  const int N = 1024, K = 1024;
  __shared__ short As[128 * 64];
  __shared__ short Bs[128 * 64];

  const int tm = blockIdx.x & 31;
  const int tn = blockIdx.x >> 5;
  const int m0 = tm * 128, n0 = tn * 128;

  const int tid = threadIdx.x;
  const int lane = tid & 63;
  const int w = tid >> 6;
  const int wr = w >> 1, wc = w & 1;
  const int hi = lane >> 4, cc = lane & 15;
  const int srow = lane >> 3, schunk = lane & 7;

  f32x4 acc[4][4] = {};

  for (int kt = 0; kt < 16; ++kt) {
    const int k0 = kt * 64;
#pragma unroll
    for (int i = 0; i < 4; ++i) {
      const int ri = w * 4 + i;
      const int row = ri * 8 + srow;
      const int gch = schunk ^ (row & 7);
      async_copy16(A + (size_t)(m0 + row) * K + (k0 + gch * 8), &As[ri * 512]);
      async_copy16(Wt + (size_t)(n0 + row) * K + (k0 + gch * 8), &Bs[ri * 512]);
    }
    __syncthreads();
#pragma unroll
    for (int kk = 0; kk < 2; ++kk) {
      bf16x8 af[4], bfr[4];
#pragma unroll
      for (int x = 0; x < 4; ++x) {
        const int gch = kk * 4 + hi;
        const int rowA = wr * 64 + x * 16 + cc;
        af[x] = *(const bf16x8*)&As[rowA * 64 + ((gch ^ (rowA & 7)) << 3)];
        const int rowB = wc * 64 + x * 16 + cc;
        bfr[x] = *(const bf16x8*)&Bs[rowB * 64 + ((gch ^ (rowB & 7)) << 3)];
      }
#pragma unroll
      for (int x = 0; x < 4; ++x)
#pragma unroll
        for (int yy = 0; yy < 4; ++yy)
          acc[x][yy] = MFMA16x16x32(af[x], bfr[yy], acc[x][yy], 0, 0, 0);
    }
    __syncthreads();
  }

#pragma unroll
  for (int x = 0; x < 4; ++x) {
    const int rbase = m0 + wr * 64 + x * 16 + (hi << 2);
#pragma unroll
    for (int yy = 0; yy < 4; ++yy) {
      const int col = n0 + wc * 64 + yy * 16 + cc;
      const float bv = bias[col];
#pragma unroll
      for (int r = 0; r < 4; ++r)
        C[(size_t)(rbase + r) * N + col] = acc[x][yy][r] + bv;
    }
  }
}

// ---------- flash attention (swapped ops, 32 q/wave, static-shift softmax) ----------
// grid (16, 16, 2) = 512 blocks; 4 waves x 32 q-rows; KVBLK=64, K/V dbuf.
__launch_bounds__(256, 2)
__global__ void attn_kernel(const short* __restrict__ qh,
                            const short* __restrict__ kh,
                            const short* __restrict__ Vt,
                            short* __restrict__ concat) {
  const int S = 2048;
  const float CL2 = 0.18033688011112042f;  // 0.125 * log2(e)
  __shared__ short Ks[2][64 * 64];
  __shared__ short Vs[2][64 * 64];
  __shared__ short Ps[4 * 32 * 64];

  const int qb = blockIdx.x;
  const int h = blockIdx.y;
  const int b = blockIdx.z;
  const int tid = threadIdx.x, lane = tid & 63, w = tid >> 6;
  const int hi = lane >> 4, cc = lane & 15;

  const size_t rowbase = (size_t)b * S;
  const int q0 = qb * 128 + w * 32;

  // Q fragments, B-operand: col = q, k = hi*8+i (+32 per kk); 2 q-frags
  bf16x8 qf[2][2];
#pragma unroll
  for (int aq = 0; aq < 2; ++aq)
#pragma unroll
    for (int kk = 0; kk < 2; ++kk) {
      const int col = h * 64 + kk * 32 + hi * 8;
      qf[aq][kk] =
          *(const bf16x8*)&qh[(rowbase + q0 + aq * 16 + cc) * 1024 + col];
    }

  f32x4 oacc[2][4] = {};
  float l[2] = {0.f, 0.f};

  const short* Vth = Vt + (size_t)(b * 16 + h) * 64 * 2048;
  short* Pw = &Ps[w * 2048];
  const int srow = lane >> 3, schunk = lane & 7;
  const int e0 = (cc >> 3) & 1;

  // prologue: stage tile 0 into buf 0
#pragma unroll
  for (int i = 0; i < 2; ++i) {
    const int ri = w * 2 + i;
    const int row = ri * 8 + srow;
    const int gch = schunk ^ (row & 7);
    async_copy16(&kh[(rowbase + row) * 1024 + h * 64 + gch * 8], &Ks[0][ri * 512]);
    async_copy16(&Vth[(size_t)row * 2048 + gch * 8], &Vs[0][ri * 512]);
  }
  __syncthreads();

  for (int t = 0; t < S / 64; ++t) {
    const int cur = t & 1;
    if (t + 1 < S / 64) {  // issue next-tile stage before computing current
      const int kv0 = (t + 1) * 64;
#pragma unroll
      for (int i = 0; i < 2; ++i) {
        const int ri = w * 2 + i;
        const int row = ri * 8 + srow;
        const int gch = schunk ^ (row & 7);
        async_copy16(&kh[(rowbase + kv0 + row) * 1024 + h * 64 + gch * 8],
                     &Ks[cur ^ 1][ri * 512]);
        async_copy16(&Vth[(size_t)row * 2048 + kv0 + gch * 8],
                     &Vs[cur ^ 1][ri * 512]);
      }
    }

    // QK^T swapped: sacc[aq][n] = mfma(K_frag(n), Q_aq) -> D[kv][q]
    f32x4 sacc[2][4] = {};
#pragma unroll
    for (int kk = 0; kk < 2; ++kk) {
      bf16x8 kf[4];
#pragma unroll
      for (int n = 0; n < 4; ++n) {
        const int row = n * 16 + cc;
        const int ch = (kk * 4 + hi) ^ (cc & 7);
        kf[n] = *(const bf16x8*)&Ks[cur][row * 64 + (ch << 3)];
      }
#pragma unroll
      for (int aq = 0; aq < 2; ++aq)
#pragma unroll
        for (int n = 0; n < 4; ++n)
          sacc[aq][n] = MFMA16x16x32(kf[n], qf[aq][kk], sacc[aq][n], 0, 0, 0);
    }

    // static-shift softmax: p = 2^(s*CL2); lane owns q-row aq*16+cc
#pragma unroll
    for (int aq = 0; aq < 2; ++aq) {
      const int qrow = aq * 16 + cc;
#pragma unroll
      for (int n = 0; n < 4; ++n) {
        const float p0 = exp2_fast(sacc[aq][n][0] * CL2);
        const float p1 = exp2_fast(sacc[aq][n][1] * CL2);
        const float p2 = exp2_fast(sacc[aq][n][2] * CL2);
        const float p3 = exp2_fast(sacc[aq][n][3] * CL2);
        l[aq] += (p0 + p1) + (p2 + p3);
        const uint32_t u0 = cvt_pk_bf16(p0, p1);
        const uint32_t u1 = cvt_pk_bf16(p2, p3);
        const int chunk = (2 * n + (hi >> 1)) ^ (cc & 7);
        const int base = qrow * 64 + (chunk << 3) + ((hi & 1) << 2);
        // two b32 writes, word-parity split -> 32 distinct banks per phase
        *(uint32_t*)&Pw[base + (e0 << 1)] = e0 ? u1 : u0;
        *(uint32_t*)&Pw[base + ((e0 ^ 1) << 1)] = e0 ? u0 : u1;
      }
    }

    // PV swapped: oacc[aq][n] = mfma(V^T_frag(n), P_aq) -> D[d][q]
#pragma unroll
    for (int kvh = 0; kvh < 2; ++kvh) {
      const int ch = (kvh * 4 + hi) ^ (cc & 7);
      bf16x8 pf[2], vf[4];
#pragma unroll
      for (int aq = 0; aq < 2; ++aq)
        pf[aq] = *(const bf16x8*)&Pw[(aq * 16 + cc) * 64 + (ch << 3)];
#pragma unroll
      for (int n = 0; n < 4; ++n) {
        const int row = n * 16 + cc;
        vf[n] = *(const bf16x8*)&Vs[cur][row * 64 + (ch << 3)];
      }
#pragma unroll
      for (int aq = 0; aq < 2; ++aq)
#pragma unroll
        for (int n = 0; n < 4; ++n)
          oacc[aq][n] = MFMA16x16x32(vf[n], pf[aq], oacc[aq][n], 0, 0, 0);
    }
    __syncthreads();  // next-tile stage drained; buf[cur] free to overwrite
  }

  // epilogue: finish row-sums across the 4 lanes sharing q, normalize, store
#pragma unroll
  for (int aq = 0; aq < 2; ++aq) {
    float lv = l[aq];
    lv += __shfl_xor(lv, 16);
    lv += __shfl_xor(lv, 32);
    const float inv = 1.0f / lv;
    const size_t grow = rowbase + q0 + aq * 16 + cc;
#pragma unroll
    for (int n = 0; n < 4; ++n)
#pragma unroll
      for (int r = 0; r < 4; ++r) {
        const int d = n * 16 + hi * 4 + r;
        concat[grow * 1024 + h * 64 + d] = f2b(oacc[aq][n][r] * inv);
      }
  }
}

// ---------- launch ----------
extern "C" void kernel_launch(void* const* d_in, const int* in_sizes, int n_in,
                              void* d_out, int out_size, void* d_ws, size_t ws_size,
                              hipStream_t stream) {
  const float* q = (const float*)d_in[0];
  const float* k = (const float*)d_in[1];
  const float* v = (const float*)d_in[2];
  const float* WQ = (const float*)d_in[3];
  const float* bQ = (const float*)d_in[4];
  const float* WK = (const float*)d_in[5];
  const float* bK = (const float*)d_in[6];
  const float* WV = (const float*)d_in[7];
  const float* bV = (const float*)d_in[8];
  const float* WO = (const float*)d_in[9];
  const float* bO = (const float*)d_in[10];

  char* ws = (char*)d_ws;
  const size_t MB = 1024 * 1024;
  // 48 MB layout (proven in round 3):
  short* Wt = (short*)ws;              // 0..8   MB: weights bf16, transposed
  short* xq = (short*)(ws + 8 * MB);   // 8..16  MB: bf16(q); later Vt
  short* xk = (short*)(ws + 16 * MB);  // 16..24 MB: bf16(k); later concat
  short* xv = (short*)(ws + 24 * MB);  // 24..32 MB: bf16(v)
  short* qh = (short*)(ws + 32 * MB);  // 32..40 MB
  short* kh = (short*)(ws + 40 * MB);  // 40..48 MB
  short* Vt = xq;       // xq dead after the Q/K gemm dispatch
  short* concat = xk;   // xk dead after the Q/K gemm dispatch

  // 1) weights: transpose + convert
  transpose4_kernel<<<dim3(16, 16, 4), 256, 0, stream>>>(WQ, WK, WV, WO, Wt);
  // 2) q,k,v: fp32 -> bf16 (one pass, 3 tensors)
  cvt3_kernel<<<dim3(2048, 3), 256, 0, stream>>>(q, k, v, xq, xk, xv);
  // 3a) Q,K projections (slices 0,1)
  gemm_qkv_kernel<<<dim3(256, 2), 256, 0, stream>>>(
      xq, xk, xv, Wt, bQ, bK, bV, qh, kh, Vt, 0);
  // 3b) V projection (slice 2) -> Vt (reuses xq slot; xq dead)
  gemm_qkv_kernel<<<dim3(256, 1), 256, 0, stream>>>(
      xq, xk, xv, Wt, bQ, bK, bV, qh, kh, Vt, 2);
  // 4) flash attention -> concat [b*s][h*hd] (reuses xk slot; xk dead)
  attn_kernel<<<dim3(16, 16, 2), 256, 0, stream>>>(qh, kh, Vt, concat);
  // 5) output projection -> d_out (fp32)
  gemm_out_kernel<<<256, 256, 0, stream>>>(concat, Wt + 3 * MB, bO,
                                           (float*)d_out);
}